// Round 5
// baseline (1320.505 us; speedup 1.0000x reference)
//
#include <hip/hip_runtime.h>
#include <hip/hip_bf16.h>

typedef __attribute__((ext_vector_type(8))) short bf16x8;
typedef __attribute__((ext_vector_type(4))) float f32x4;
typedef unsigned short u16;
typedef unsigned int u32;

__device__ __forceinline__ u32 bf16_rne(float f) {
  u32 u = __float_as_uint(f);
  return (u + 0x7FFFu + ((u >> 16) & 1u)) >> 16;
}
__device__ __forceinline__ float bf16_val(u32 b) { return __uint_as_float(b << 16); }

__device__ __forceinline__ void g2l16(const u16* g, u16* l) {
  __builtin_amdgcn_global_load_lds(
      (const __attribute__((address_space(1))) u32*)g,
      (__attribute__((address_space(3))) u32*)l, 16, 0, 0);
}

// ---- split fp32 array into bf16 hi/lo (no transpose) ----
__global__ void split_arr(const float* __restrict__ in,
                          u16* __restrict__ hi, u16* __restrict__ lo, int n4) {
  int i = blockIdx.x * 256 + threadIdx.x;
  if (i >= n4) return;
  float4 v = ((const float4*)in)[i];
  u32 h0 = bf16_rne(v.x), h1 = bf16_rne(v.y), h2 = bf16_rne(v.z), h3 = bf16_rne(v.w);
  u32 l0 = bf16_rne(v.x - bf16_val(h0));
  u32 l1 = bf16_rne(v.y - bf16_val(h1));
  u32 l2 = bf16_rne(v.z - bf16_val(h2));
  u32 l3 = bf16_rne(v.w - bf16_val(h3));
  ushort4 hv; hv.x = (u16)h0; hv.y = (u16)h1; hv.z = (u16)h2; hv.w = (u16)h3;
  ushort4 lv; lv.x = (u16)l0; lv.y = (u16)l1; lv.z = (u16)l2; lv.w = (u16)l3;
  ((ushort4*)hi)[i] = hv;
  ((ushort4*)lo)[i] = lv;
}

// ---- transpose each 256x256 fp32 slice and split into bf16 hi/lo arrays ----
__global__ void split_transpose256(const float* __restrict__ in,
                                   u16* __restrict__ hi, u16* __restrict__ lo) {
  __shared__ float tile[32][33];
  const size_t off = (size_t)blockIdx.z * 65536;
  const int tx = threadIdx.x, ty = threadIdx.y;
#pragma unroll
  for (int i = 0; i < 4; ++i) {
    int y = blockIdx.y * 32 + ty + i * 8;
    int x = blockIdx.x * 32 + tx;
    tile[ty + i * 8][tx] = in[off + (size_t)y * 256 + x];
  }
  __syncthreads();
#pragma unroll
  for (int i = 0; i < 4; ++i) {
    float v = tile[tx][ty + i * 8];
    u32 hb = bf16_rne(v);
    u32 lb = bf16_rne(v - bf16_val(hb));
    size_t idx = off + (size_t)(blockIdx.x * 32 + ty + i * 8) * 256 + blockIdx.y * 32 + tx;
    hi[idx] = (u16)hb;
    lo[idx] = (u16)lb;
  }
}

// ---------------- fused priors-GEMM (split-bf16) + dynamic routing ----------------
// ROUND-5 STRUCTURE: M=128/block, 256 threads = 4 waves (pure eg roles), wave tile
// 128x64 (acc[8][4] = 128 regs). W fragments are loaded GLOBAL->VGPR (L2-resident,
// one-k-step register prefetch) instead of through LDS: round-4 analysis showed the
// GEMM phase was LDS-pipe-bound (144KB/k-step vs 128B/cyc) and LDS-capacity-bound
// (68KB -> 2 blocks/CU). W-in-regs cuts LDS traffic to 80KB/k-step AND shrinks LDS
// to ~35KB -> FOUR blocks/CU (__launch_bounds__(256,4), 16 waves/CU).
// A stays in LDS (its 4x read redundancy would swamp L2 if moved to global).
// Row r = mt*16 + q*4 + rr (all rows in every wave); col e = eg*64 + ct*16 + li.
// A: double-buffered 16KB slices via global_load_lds, k-granule XOR swizzle
// (source pre-swizzled, linear LDS dest, readers pick slot q ^ ((li>>1)&3)).
// One barrier per k-step (vmcnt(0) drain: all loads issued ~2000cyc earlier).
template <int R>
__global__ __launch_bounds__(256, 4) void caps_route(
    const u16* __restrict__ Ahi_g,   // [ab][128 rows][256] bf16-hi
    const u16* __restrict__ Alo_g,
    const u16* __restrict__ Whi,     // [KN][256][256] (transposed [e][d])
    const u16* __restrict__ Wlo,
    u16* __restrict__ o1hi, u16* __restrict__ o1lo,   // stage1 out (split)
    float* __restrict__ outp,                          // stage2 out
    int KN, int stage) {
  constexpr int APB = 128 / R;              // routings per block (1 or 2)
  constexpr int SEG = APB;                  // segments per wave
  constexpr int MTS = 8 / SEG;              // m-tiles per segment
  constexpr int ABS = (R == 128) ? 6 : 5;   // log2(a-blocks in grid)
  __shared__ __align__(16) u16 Ab[2][8192];  // A dbuf: [Ahi(8KB) | Alo(8KB)] per slice
  __shared__ __align__(16) float wlog[4][128];
  __shared__ __align__(16) float probs[128];
  __shared__ float sqpart[2][4];

  const int tid = threadIdx.x;
  const int w = tid >> 6, lane = tid & 63, q = lane >> 4, li = lane & 15;
  const int eg = w;                         // wave = column group
  const int kk = blockIdx.x >> ABS;         // weight slice (h or c)
  const int ab = blockIdx.x & ((1 << ABS) - 1);

  // ---- A staging: wave w stages chunks {2w, 2w+1} of hi and lo (4 DMAs/wave) ----
  const int sub = lane >> 2, p = lane & 3;
  const int gslot = p ^ ((sub >> 1) & 3);              // pre-swizzled k-granule
  const size_t lane_off = (size_t)sub * 256 + gslot * 8;
  const u16* gAh = Ahi_g + (size_t)ab * 32768 + (size_t)(2 * w) * 4096 + lane_off;
  const u16* gAl = Alo_g + (size_t)ab * 32768 + (size_t)(2 * w) * 4096 + lane_off;

  auto STAGE = [&](int ko, int nb) {
    u16* d = &Ab[nb][(2 * w) * 512] + lane * 8;        // linear LDS dest (DMA rule)
    g2l16(gAh + ko, d);
    g2l16(gAh + ko + 4096, d + 512);
    g2l16(gAl + ko, d + 4096);
    g2l16(gAl + ko + 4096, d + 4608);
  };

  // ---- W fragment global pointers (direct global->VGPR, no LDS, no swizzle) ----
  // frag (ct, ks): gW? + ct*4096 + ks*32 ; 16B per lane, rows e = eg*64+ct*16+li.
  const u16* gWh = Whi + (size_t)kk * 65536 + (size_t)(eg * 64 + li) * 256 + q * 8;
  const u16* gWl = Wlo + (size_t)kk * 65536 + (size_t)(eg * 64 + li) * 256 + q * 8;

  // ---- A fragment read offset (swizzled slot) ----
  const int rslot = q ^ ((li >> 1) & 3);
  const int fbase = li * 32 + rslot * 8;               // u16 units within a chunk

  f32x4 acc[8][4] = {};

  // prologue: W frags for ks=0 -> regs; A slice 0 -> LDS
  bf16x8 bh[4], bl[4];
#pragma unroll
  for (int ct = 0; ct < 4; ++ct) {
    bh[ct] = *(const bf16x8*)(gWh + ct * 4096);
    bl[ct] = *(const bf16x8*)(gWl + ct * 4096);
  }
  STAGE(0, 0);
  asm volatile("s_waitcnt vmcnt(0)" ::: "memory");
  __builtin_amdgcn_s_barrier();

  // ---- GEMM main loop: P = A (128 x 256) @ W[kk] (256 x 256), split-bf16 3-MFMA ----
#pragma unroll
  for (int ks = 0; ks < 8; ++ks) {
    bf16x8 nbh[4], nbl[4];
    if (ks < 7) {
      STAGE((ks + 1) * 32, (ks + 1) & 1);              // A DMA next slice
#pragma unroll
      for (int ct = 0; ct < 4; ++ct) {                 // W regs next slice
        nbh[ct] = *(const bf16x8*)(gWh + ct * 4096 + (ks + 1) * 32);
        nbl[ct] = *(const bf16x8*)(gWl + ct * 4096 + (ks + 1) * 32);
      }
    }
    const u16* aB = &Ab[ks & 1][0] + fbase;
#pragma unroll
    for (int mt = 0; mt < 8; ++mt) {
      bf16x8 ah = *(const bf16x8*)(aB + mt * 512);
      bf16x8 al = *(const bf16x8*)(aB + mt * 512 + 4096);
#pragma unroll
      for (int ct = 0; ct < 4; ++ct) {
        acc[mt][ct] = __builtin_amdgcn_mfma_f32_16x16x32_bf16(al, bh[ct], acc[mt][ct], 0, 0, 0);
        acc[mt][ct] = __builtin_amdgcn_mfma_f32_16x16x32_bf16(ah, bl[ct], acc[mt][ct], 0, 0, 0);
        acc[mt][ct] = __builtin_amdgcn_mfma_f32_16x16x32_bf16(ah, bh[ct], acc[mt][ct], 0, 0, 0);
      }
    }
    asm volatile("s_waitcnt vmcnt(0)" ::: "memory");   // next A slice + W regs landed
    __builtin_amdgcn_s_barrier();
    if (ks < 7) {
#pragma unroll
      for (int ct = 0; ct < 4; ++ct) { bh[ct] = nbh[ct]; bl[ct] = nbl[ct]; }
    }
  }

  // ---- dynamic routing (3 iterations), APB independent routings, all wave-local ----
  const float invR = 1.0f / R;
  float v[SEG][4];
  float lg0 = 0.f, lg1 = 0.f;                          // running logits (all waves)

  for (int iter = 0; iter < 3; ++iter) {
    float4 p4[8];
    if (iter == 0) {
#pragma unroll
      for (int mt = 0; mt < 8; ++mt) {
        p4[mt].x = invR; p4[mt].y = invR; p4[mt].z = invR; p4[mt].w = invR;
      }
    } else {
#pragma unroll
      for (int mt = 0; mt < 8; ++mt)
        p4[mt] = *(const float4*)&probs[mt * 16 + q * 4];
    }
    // s[a][e] = sum_b probs[b] * P[b,e] : in-lane over (mt,rr), shfl over q
    float s[SEG][4];
#pragma unroll
    for (int sg = 0; sg < SEG; ++sg) {
#pragma unroll
      for (int ct = 0; ct < 4; ++ct) {
        float t = 0.f;
#pragma unroll
        for (int mi = 0; mi < MTS; ++mi) {
          const int mt = sg * MTS + mi;
          t += p4[mt].x * acc[mt][ct][0] + p4[mt].y * acc[mt][ct][1] +
               p4[mt].z * acc[mt][ct][2] + p4[mt].w * acc[mt][ct][3];
        }
        t += __shfl_xor(t, 16);
        t += __shfl_xor(t, 32);
        s[sg][ct] = t;
      }
    }
    // squash: sq_a = sum_e s_a[e]^2 over 256 e (LDS over eg)
#pragma unroll
    for (int sg = 0; sg < SEG; ++sg) {
      float ss = s[sg][0] * s[sg][0] + s[sg][1] * s[sg][1] +
                 s[sg][2] * s[sg][2] + s[sg][3] * s[sg][3];
      ss += __shfl_xor(ss, 1); ss += __shfl_xor(ss, 2);
      ss += __shfl_xor(ss, 4); ss += __shfl_xor(ss, 8);
      if (lane == 0) sqpart[sg][eg] = ss;
    }
    __syncthreads();
#pragma unroll
    for (int sg = 0; sg < SEG; ++sg) {
      float sq = sqpart[sg][0] + sqpart[sg][1] + sqpart[sg][2] + sqpart[sg][3];
      float scale = (sq > 0.f) ? sq / ((1.0f + sq) * sqrtf(sq)) : 0.f;
#pragma unroll
      for (int ct = 0; ct < 4; ++ct) v[sg][ct] = s[sg][ct] * scale;
    }

    if (iter < 2) {
      // logits[b] += sum_e P[b,e] * v[a(b)][e] : in-lane over ct, shfl over li, LDS over eg
#pragma unroll
      for (int mt = 0; mt < 8; ++mt) {
        const int sg = mt / MTS;
        float tt[4];
#pragma unroll
        for (int rr = 0; rr < 4; ++rr) {
          float t = acc[mt][0][rr] * v[sg][0] + acc[mt][1][rr] * v[sg][1] +
                    acc[mt][2][rr] * v[sg][2] + acc[mt][3][rr] * v[sg][3];
          t += __shfl_xor(t, 1); t += __shfl_xor(t, 2);
          t += __shfl_xor(t, 4); t += __shfl_xor(t, 8);
          tt[rr] = t;
        }
        if (li == 0)
          *(float4*)&wlog[eg][mt * 16 + q * 4] = make_float4(tt[0], tt[1], tt[2], tt[3]);
      }
      __syncthreads();
      // all-wave redundant softmax (identical values; each wave reads its own writes)
      if (R == 128) {
        int r0 = lane, r1 = lane + 64;   // one routing over 128 rows
        lg0 += wlog[0][r0] + wlog[1][r0] + wlog[2][r0] + wlog[3][r0];
        lg1 += wlog[0][r1] + wlog[1][r1] + wlog[2][r1] + wlog[3][r1];
        float m = fmaxf(lg0, lg1);
#pragma unroll
        for (int d2 = 1; d2 < 64; d2 <<= 1) m = fmaxf(m, __shfl_xor(m, d2));
        float e0 = __expf(lg0 - m), e1 = __expf(lg1 - m);
        float zz = e0 + e1;
#pragma unroll
        for (int d2 = 1; d2 < 64; d2 <<= 1) zz += __shfl_xor(zz, d2);
        float inv = 1.0f / zz;
        probs[r0] = e0 * inv;
        probs[r1] = e1 * inv;
      } else {
        int r0 = lane, r1 = lane + 64;   // two routings (rows 0..63 = a0, 64..127 = a1)
        lg0 += wlog[0][r0] + wlog[1][r0] + wlog[2][r0] + wlog[3][r0];
        lg1 += wlog[0][r1] + wlog[1][r1] + wlog[2][r1] + wlog[3][r1];
        float m0 = lg0, m1 = lg1;
#pragma unroll
        for (int d2 = 1; d2 < 64; d2 <<= 1) {
          m0 = fmaxf(m0, __shfl_xor(m0, d2));
          m1 = fmaxf(m1, __shfl_xor(m1, d2));
        }
        float e0 = __expf(lg0 - m0), e1 = __expf(lg1 - m1);
        float z0 = e0, z1 = e1;
#pragma unroll
        for (int d2 = 1; d2 < 64; d2 <<= 1) {
          z0 += __shfl_xor(z0, d2);
          z1 += __shfl_xor(z1, d2);
        }
        probs[r0] = e0 / z0;
        probs[r1] = e1 / z1;
      }
      asm volatile("s_waitcnt lgkmcnt(0)" ::: "memory");  // writes land before next-iter reads
    }
  }

  // ---- epilogue. stage1 -> split out1[a][kk][e]; stage2 -> fp32 out[kk][a][e] ----
  if (q == 0) {
#pragma unroll
    for (int sg = 0; sg < SEG; ++sg) {
      const int ag = ab * APB + sg;      // global a
      if (stage == 1) {
        size_t ob = ((size_t)ag * KN + kk) * 256;
#pragma unroll
        for (int ct = 0; ct < 4; ++ct) {
          int e = eg * 64 + ct * 16 + li;
          u32 hb = bf16_rne(v[sg][ct]);
          u32 lb = bf16_rne(v[sg][ct] - bf16_val(hb));
          o1hi[ob + e] = (u16)hb;
          o1lo[ob + e] = (u16)lb;
        }
      } else {
        size_t ob = ((size_t)kk * 64 + ag) * 256;
#pragma unroll
        for (int ct = 0; ct < 4; ++ct) {
          int e = eg * 64 + ct * 16 + li;
          outp[ob + e] = v[sg][ct];
        }
      }
    }
  }
}

extern "C" void kernel_launch(void* const* d_in, const int* in_sizes, int n_in,
                              void* d_out, int out_size, void* d_ws, size_t ws_size,
                              hipStream_t stream) {
  const float* x  = (const float*)d_in[0];   // [64][128][256]
  const float* w1 = (const float*)d_in[1];   // [64][256][256]
  const float* wc = (const float*)d_in[2];   // [32][256][256]
  float* out = (float*)d_out;                // [32][64][256]

  char* ws = (char*)d_ws;
  u16* w1hi = (u16*)(ws);                    // 8 MB
  u16* w1lo = (u16*)(ws + (8u << 20));       // 8 MB
  u16* wchi = (u16*)(ws + (16u << 20));      // 4 MB
  u16* wclo = (u16*)(ws + (20u << 20));      // 4 MB
  u16* xhi  = (u16*)(ws + (24u << 20));      // 4 MB
  u16* xlo  = (u16*)(ws + (28u << 20));      // 4 MB
  u16* o1hi = (u16*)(ws + (32u << 20));      // 2 MB
  u16* o1lo = (u16*)(ws + (34u << 20));      // 2 MB

  split_arr<<<2048, 256, 0, stream>>>(x, xhi, xlo, 524288);
  split_transpose256<<<dim3(8, 8, 64), dim3(32, 8), 0, stream>>>(w1, w1hi, w1lo);
  split_transpose256<<<dim3(8, 8, 32), dim3(32, 8), 0, stream>>>(wc, wchi, wclo);
  // stage 1: 64 kk x 64 a-blocks (M=128 = 1 routing of R=128), 4 blocks/CU
  caps_route<128><<<64 * 64, 256, 0, stream>>>(xhi, xlo, w1hi, w1lo, o1hi, o1lo, nullptr, 64, 1);
  // stage 2: 32 kk x 32 a-blocks (M=128 = 2 routings of R=64), 4 blocks/CU
  caps_route<64><<<32 * 32, 256, 0, stream>>>(o1hi, o1lo, wchi, wclo, nullptr, nullptr, out, 32, 2);
}

// Round 6
// 373.158 us; speedup vs baseline: 3.5387x; 3.5387x over previous
//
#include <hip/hip_runtime.h>
#include <hip/hip_bf16.h>

typedef __attribute__((ext_vector_type(8))) short bf16x8;
typedef __attribute__((ext_vector_type(4))) float f32x4;
typedef unsigned short u16;
typedef unsigned int u32;

__device__ __forceinline__ u32 bf16_rne(float f) {
  u32 u = __float_as_uint(f);
  return (u + 0x7FFFu + ((u >> 16) & 1u)) >> 16;
}
__device__ __forceinline__ float bf16_val(u32 b) { return __uint_as_float(b << 16); }

__device__ __forceinline__ void g2l16(const u16* g, u16* l) {
  __builtin_amdgcn_global_load_lds(
      (const __attribute__((address_space(1))) u32*)g,
      (__attribute__((address_space(3))) u32*)l, 16, 0, 0);
}

// ---- split fp32 array into bf16 hi/lo (no transpose) ----
__global__ void split_arr(const float* __restrict__ in,
                          u16* __restrict__ hi, u16* __restrict__ lo, int n4) {
  int i = blockIdx.x * 256 + threadIdx.x;
  if (i >= n4) return;
  float4 v = ((const float4*)in)[i];
  u32 h0 = bf16_rne(v.x), h1 = bf16_rne(v.y), h2 = bf16_rne(v.z), h3 = bf16_rne(v.w);
  u32 l0 = bf16_rne(v.x - bf16_val(h0));
  u32 l1 = bf16_rne(v.y - bf16_val(h1));
  u32 l2 = bf16_rne(v.z - bf16_val(h2));
  u32 l3 = bf16_rne(v.w - bf16_val(h3));
  ushort4 hv; hv.x = (u16)h0; hv.y = (u16)h1; hv.z = (u16)h2; hv.w = (u16)h3;
  ushort4 lv; lv.x = (u16)l0; lv.y = (u16)l1; lv.z = (u16)l2; lv.w = (u16)l3;
  ((ushort4*)hi)[i] = hv;
  ((ushort4*)lo)[i] = lv;
}

// ---- transpose each 256x256 fp32 slice and split into bf16 hi/lo arrays ----
__global__ void split_transpose256(const float* __restrict__ in,
                                   u16* __restrict__ hi, u16* __restrict__ lo) {
  __shared__ float tile[32][33];
  const size_t off = (size_t)blockIdx.z * 65536;
  const int tx = threadIdx.x, ty = threadIdx.y;
#pragma unroll
  for (int i = 0; i < 4; ++i) {
    int y = blockIdx.y * 32 + ty + i * 8;
    int x = blockIdx.x * 32 + tx;
    tile[ty + i * 8][tx] = in[off + (size_t)y * 256 + x];
  }
  __syncthreads();
#pragma unroll
  for (int i = 0; i < 4; ++i) {
    float v = tile[tx][ty + i * 8];
    u32 hb = bf16_rne(v);
    u32 lb = bf16_rne(v - bf16_val(hb));
    size_t idx = off + (size_t)(blockIdx.x * 32 + ty + i * 8) * 256 + blockIdx.y * 32 + tx;
    hi[idx] = (u16)hb;
    lo[idx] = (u16)lb;
  }
}

// ---------------- fused priors-GEMM (split-bf16) + dynamic routing ----------------
// ROUND-6 = ROUND-5 STRUCTURE WITH LEGAL REGISTER BUDGET.
// M=128/block, 256 threads = 4 waves (pure eg roles), wave tile 128x64
// (acc[8][4] = 128 regs). __launch_bounds__(256, 2): 2 waves/SIMD -> 256-reg
// budget. HARD CONSTRAINT (round-1 + round-5 spills): acc alone is 128 regs,
// so >128 regs/wave is unavoidable -> occupancy caps at 2 waves/SIMD
// (m69 reg-occupancy steps 64/128/256). Round-5's (256,4) forced a 128-reg
// budget -> 2.7GB scratch spill, 4x slower. Occupancy is NOT a lever here;
// per-block efficiency is.
// W fragments: GLOBAL->VGPR with one-k-step register prefetch (L2-resident;
// 64 blocks share each kk slice). Removes W's LDS write+read (144->80 KB
// LDS traffic per k-step) and the mid-step lgkm barrier (1 barrier/k-step).
// A stays in LDS (4x read redundancy would swamp L2 if moved to global):
// double-buffered 16KB slices via global_load_lds, k-granule XOR swizzle
// (source pre-swizzled, linear LDS dest, readers pick slot q ^ ((li>>1)&3)).
// Row r = mt*16 + q*4 + rr (all rows in every wave); col e = eg*64 + ct*16 + li.
template <int R>
__global__ __launch_bounds__(256, 2) void caps_route(
    const u16* __restrict__ Ahi_g,   // [ab][128 rows][256] bf16-hi
    const u16* __restrict__ Alo_g,
    const u16* __restrict__ Whi,     // [KN][256][256] (transposed [e][d])
    const u16* __restrict__ Wlo,
    u16* __restrict__ o1hi, u16* __restrict__ o1lo,   // stage1 out (split)
    float* __restrict__ outp,                          // stage2 out
    int KN, int stage) {
  constexpr int APB = 128 / R;              // routings per block (1 or 2)
  constexpr int SEG = APB;                  // segments per wave
  constexpr int MTS = 8 / SEG;              // m-tiles per segment
  constexpr int ABS = (R == 128) ? 6 : 5;   // log2(a-blocks in grid)
  __shared__ __align__(16) u16 Ab[2][8192];  // A dbuf: [Ahi(8KB) | Alo(8KB)] per slice
  __shared__ __align__(16) float wlog[4][128];
  __shared__ __align__(16) float probs[128];
  __shared__ float sqpart[2][4];

  const int tid = threadIdx.x;
  const int w = tid >> 6, lane = tid & 63, q = lane >> 4, li = lane & 15;
  const int eg = w;                         // wave = column group
  const int kk = blockIdx.x >> ABS;         // weight slice (h or c)
  const int ab = blockIdx.x & ((1 << ABS) - 1);

  // ---- A staging: wave w stages chunks {2w, 2w+1} of hi and lo (4 DMAs/wave) ----
  const int sub = lane >> 2, p = lane & 3;
  const int gslot = p ^ ((sub >> 1) & 3);              // pre-swizzled k-granule
  const size_t lane_off = (size_t)sub * 256 + gslot * 8;
  const u16* gAh = Ahi_g + (size_t)ab * 32768 + (size_t)(2 * w) * 4096 + lane_off;
  const u16* gAl = Alo_g + (size_t)ab * 32768 + (size_t)(2 * w) * 4096 + lane_off;

  auto STAGE = [&](int ko, int nb) {
    u16* d = &Ab[nb][(2 * w) * 512] + lane * 8;        // linear LDS dest (DMA rule)
    g2l16(gAh + ko, d);
    g2l16(gAh + ko + 4096, d + 512);
    g2l16(gAl + ko, d + 4096);
    g2l16(gAl + ko + 4096, d + 4608);
  };

  // ---- W fragment global pointers (direct global->VGPR, no LDS, no swizzle) ----
  // frag (ct, ks): gW? + ct*4096 + ks*32 ; 16B per lane, rows e = eg*64+ct*16+li.
  const u16* gWh = Whi + (size_t)kk * 65536 + (size_t)(eg * 64 + li) * 256 + q * 8;
  const u16* gWl = Wlo + (size_t)kk * 65536 + (size_t)(eg * 64 + li) * 256 + q * 8;

  // ---- A fragment read offset (swizzled slot) ----
  const int rslot = q ^ ((li >> 1) & 3);
  const int fbase = li * 32 + rslot * 8;               // u16 units within a chunk

  f32x4 acc[8][4] = {};

  // prologue: W frags for ks=0 -> regs; A slice 0 -> LDS
  bf16x8 bh[4], bl[4];
#pragma unroll
  for (int ct = 0; ct < 4; ++ct) {
    bh[ct] = *(const bf16x8*)(gWh + ct * 4096);
    bl[ct] = *(const bf16x8*)(gWl + ct * 4096);
  }
  STAGE(0, 0);
  asm volatile("s_waitcnt vmcnt(0)" ::: "memory");
  __builtin_amdgcn_s_barrier();

  // ---- GEMM main loop: P = A (128 x 256) @ W[kk] (256 x 256), split-bf16 3-MFMA ----
#pragma unroll
  for (int ks = 0; ks < 8; ++ks) {
    bf16x8 nbh[4], nbl[4];
    if (ks < 7) {
      STAGE((ks + 1) * 32, (ks + 1) & 1);              // A DMA next slice
#pragma unroll
      for (int ct = 0; ct < 4; ++ct) {                 // W regs next slice
        nbh[ct] = *(const bf16x8*)(gWh + ct * 4096 + (ks + 1) * 32);
        nbl[ct] = *(const bf16x8*)(gWl + ct * 4096 + (ks + 1) * 32);
      }
    }
    const u16* aB = &Ab[ks & 1][0] + fbase;
#pragma unroll
    for (int mt = 0; mt < 8; ++mt) {
      bf16x8 ah = *(const bf16x8*)(aB + mt * 512);
      bf16x8 al = *(const bf16x8*)(aB + mt * 512 + 4096);
#pragma unroll
      for (int ct = 0; ct < 4; ++ct) {
        acc[mt][ct] = __builtin_amdgcn_mfma_f32_16x16x32_bf16(al, bh[ct], acc[mt][ct], 0, 0, 0);
        acc[mt][ct] = __builtin_amdgcn_mfma_f32_16x16x32_bf16(ah, bl[ct], acc[mt][ct], 0, 0, 0);
        acc[mt][ct] = __builtin_amdgcn_mfma_f32_16x16x32_bf16(ah, bh[ct], acc[mt][ct], 0, 0, 0);
      }
    }
    asm volatile("s_waitcnt vmcnt(0)" ::: "memory");   // next A slice + W regs landed
    __builtin_amdgcn_s_barrier();
    if (ks < 7) {
#pragma unroll
      for (int ct = 0; ct < 4; ++ct) { bh[ct] = nbh[ct]; bl[ct] = nbl[ct]; }
    }
  }

  // ---- dynamic routing (3 iterations), APB independent routings, all wave-local ----
  const float invR = 1.0f / R;
  float v[SEG][4];
  float lg0 = 0.f, lg1 = 0.f;                          // running logits (all waves)

  for (int iter = 0; iter < 3; ++iter) {
    float4 p4[8];
    if (iter == 0) {
#pragma unroll
      for (int mt = 0; mt < 8; ++mt) {
        p4[mt].x = invR; p4[mt].y = invR; p4[mt].z = invR; p4[mt].w = invR;
      }
    } else {
#pragma unroll
      for (int mt = 0; mt < 8; ++mt)
        p4[mt] = *(const float4*)&probs[mt * 16 + q * 4];
    }
    // s[a][e] = sum_b probs[b] * P[b,e] : in-lane over (mt,rr), shfl over q
    float s[SEG][4];
#pragma unroll
    for (int sg = 0; sg < SEG; ++sg) {
#pragma unroll
      for (int ct = 0; ct < 4; ++ct) {
        float t = 0.f;
#pragma unroll
        for (int mi = 0; mi < MTS; ++mi) {
          const int mt = sg * MTS + mi;
          t += p4[mt].x * acc[mt][ct][0] + p4[mt].y * acc[mt][ct][1] +
               p4[mt].z * acc[mt][ct][2] + p4[mt].w * acc[mt][ct][3];
        }
        t += __shfl_xor(t, 16);
        t += __shfl_xor(t, 32);
        s[sg][ct] = t;
      }
    }
    // squash: sq_a = sum_e s_a[e]^2 over 256 e (LDS over eg)
#pragma unroll
    for (int sg = 0; sg < SEG; ++sg) {
      float ss = s[sg][0] * s[sg][0] + s[sg][1] * s[sg][1] +
                 s[sg][2] * s[sg][2] + s[sg][3] * s[sg][3];
      ss += __shfl_xor(ss, 1); ss += __shfl_xor(ss, 2);
      ss += __shfl_xor(ss, 4); ss += __shfl_xor(ss, 8);
      if (lane == 0) sqpart[sg][eg] = ss;
    }
    __syncthreads();
#pragma unroll
    for (int sg = 0; sg < SEG; ++sg) {
      float sq = sqpart[sg][0] + sqpart[sg][1] + sqpart[sg][2] + sqpart[sg][3];
      float scale = (sq > 0.f) ? sq / ((1.0f + sq) * sqrtf(sq)) : 0.f;
#pragma unroll
      for (int ct = 0; ct < 4; ++ct) v[sg][ct] = s[sg][ct] * scale;
    }

    if (iter < 2) {
      // logits[b] += sum_e P[b,e] * v[a(b)][e] : in-lane over ct, shfl over li, LDS over eg
#pragma unroll
      for (int mt = 0; mt < 8; ++mt) {
        const int sg = mt / MTS;
        float tt[4];
#pragma unroll
        for (int rr = 0; rr < 4; ++rr) {
          float t = acc[mt][0][rr] * v[sg][0] + acc[mt][1][rr] * v[sg][1] +
                    acc[mt][2][rr] * v[sg][2] + acc[mt][3][rr] * v[sg][3];
          t += __shfl_xor(t, 1); t += __shfl_xor(t, 2);
          t += __shfl_xor(t, 4); t += __shfl_xor(t, 8);
          tt[rr] = t;
        }
        if (li == 0)
          *(float4*)&wlog[eg][mt * 16 + q * 4] = make_float4(tt[0], tt[1], tt[2], tt[3]);
      }
      __syncthreads();
      // all-wave redundant softmax (identical values; each wave reads its own writes)
      if (R == 128) {
        int r0 = lane, r1 = lane + 64;   // one routing over 128 rows
        lg0 += wlog[0][r0] + wlog[1][r0] + wlog[2][r0] + wlog[3][r0];
        lg1 += wlog[0][r1] + wlog[1][r1] + wlog[2][r1] + wlog[3][r1];
        float m = fmaxf(lg0, lg1);
#pragma unroll
        for (int d2 = 1; d2 < 64; d2 <<= 1) m = fmaxf(m, __shfl_xor(m, d2));
        float e0 = __expf(lg0 - m), e1 = __expf(lg1 - m);
        float zz = e0 + e1;
#pragma unroll
        for (int d2 = 1; d2 < 64; d2 <<= 1) zz += __shfl_xor(zz, d2);
        float inv = 1.0f / zz;
        probs[r0] = e0 * inv;
        probs[r1] = e1 * inv;
      } else {
        int r0 = lane, r1 = lane + 64;   // two routings (rows 0..63 = a0, 64..127 = a1)
        lg0 += wlog[0][r0] + wlog[1][r0] + wlog[2][r0] + wlog[3][r0];
        lg1 += wlog[0][r1] + wlog[1][r1] + wlog[2][r1] + wlog[3][r1];
        float m0 = lg0, m1 = lg1;
#pragma unroll
        for (int d2 = 1; d2 < 64; d2 <<= 1) {
          m0 = fmaxf(m0, __shfl_xor(m0, d2));
          m1 = fmaxf(m1, __shfl_xor(m1, d2));
        }
        float e0 = __expf(lg0 - m0), e1 = __expf(lg1 - m1);
        float z0 = e0, z1 = e1;
#pragma unroll
        for (int d2 = 1; d2 < 64; d2 <<= 1) {
          z0 += __shfl_xor(z0, d2);
          z1 += __shfl_xor(z1, d2);
        }
        probs[r0] = e0 / z0;
        probs[r1] = e1 / z1;
      }
      asm volatile("s_waitcnt lgkmcnt(0)" ::: "memory");  // writes land before next-iter reads
    }
  }

  // ---- epilogue. stage1 -> split out1[a][kk][e]; stage2 -> fp32 out[kk][a][e] ----
  if (q == 0) {
#pragma unroll
    for (int sg = 0; sg < SEG; ++sg) {
      const int ag = ab * APB + sg;      // global a
      if (stage == 1) {
        size_t ob = ((size_t)ag * KN + kk) * 256;
#pragma unroll
        for (int ct = 0; ct < 4; ++ct) {
          int e = eg * 64 + ct * 16 + li;
          u32 hb = bf16_rne(v[sg][ct]);
          u32 lb = bf16_rne(v[sg][ct] - bf16_val(hb));
          o1hi[ob + e] = (u16)hb;
          o1lo[ob + e] = (u16)lb;
        }
      } else {
        size_t ob = ((size_t)kk * 64 + ag) * 256;
#pragma unroll
        for (int ct = 0; ct < 4; ++ct) {
          int e = eg * 64 + ct * 16 + li;
          outp[ob + e] = v[sg][ct];
        }
      }
    }
  }
}

extern "C" void kernel_launch(void* const* d_in, const int* in_sizes, int n_in,
                              void* d_out, int out_size, void* d_ws, size_t ws_size,
                              hipStream_t stream) {
  const float* x  = (const float*)d_in[0];   // [64][128][256]
  const float* w1 = (const float*)d_in[1];   // [64][256][256]
  const float* wc = (const float*)d_in[2];   // [32][256][256]
  float* out = (float*)d_out;                // [32][64][256]

  char* ws = (char*)d_ws;
  u16* w1hi = (u16*)(ws);                    // 8 MB
  u16* w1lo = (u16*)(ws + (8u << 20));       // 8 MB
  u16* wchi = (u16*)(ws + (16u << 20));      // 4 MB
  u16* wclo = (u16*)(ws + (20u << 20));      // 4 MB
  u16* xhi  = (u16*)(ws + (24u << 20));      // 4 MB
  u16* xlo  = (u16*)(ws + (28u << 20));      // 4 MB
  u16* o1hi = (u16*)(ws + (32u << 20));      // 2 MB
  u16* o1lo = (u16*)(ws + (34u << 20));      // 2 MB

  split_arr<<<2048, 256, 0, stream>>>(x, xhi, xlo, 524288);
  split_transpose256<<<dim3(8, 8, 64), dim3(32, 8), 0, stream>>>(w1, w1hi, w1lo);
  split_transpose256<<<dim3(8, 8, 32), dim3(32, 8), 0, stream>>>(wc, wchi, wclo);
  // stage 1: 64 kk x 64 a-blocks (M=128 = 1 routing of R=128), 2 blocks/CU (reg-capped)
  caps_route<128><<<64 * 64, 256, 0, stream>>>(xhi, xlo, w1hi, w1lo, o1hi, o1lo, nullptr, 64, 1);
  // stage 2: 32 kk x 32 a-blocks (M=128 = 2 routings of R=64), 2 blocks/CU
  caps_route<64><<<32 * 32, 256, 0, stream>>>(o1hi, o1lo, wchi, wclo, nullptr, nullptr, out, 32, 2);
}

// Round 7
// 338.561 us; speedup vs baseline: 3.9004x; 1.1022x over previous
//
#include <hip/hip_runtime.h>
#include <hip/hip_bf16.h>

typedef __attribute__((ext_vector_type(8))) short bf16x8;
typedef __attribute__((ext_vector_type(4))) float f32x4;
typedef unsigned short u16;
typedef unsigned int u32;

__device__ __forceinline__ u32 bf16_rne(float f) {
  u32 u = __float_as_uint(f);
  return (u + 0x7FFFu + ((u >> 16) & 1u)) >> 16;
}
__device__ __forceinline__ float bf16_val(u32 b) { return __uint_as_float(b << 16); }

__device__ __forceinline__ void g2l16(const u16* g, u16* l) {
  __builtin_amdgcn_global_load_lds(
      (const __attribute__((address_space(1))) u32*)g,
      (__attribute__((address_space(3))) u32*)l, 16, 0, 0);
}

// ---- DPP rotation reduce within a 16-lane row: VALU pipe, not LDS ----
// (round-6 analysis: __shfl_xor = ds_bpermute/ds_swizzle on the LDS pipe, which
// is the most-contended pipe (~52%); DPP row_ror moves reduces to the VALU.)
// Rotation reduce: offsets {8}+{4}+{2}+{1} accumulate to all 16 offsets; every
// lane in the row ends with the full row sum (same postcondition as xor tree).
template <int CTRL>
__device__ __forceinline__ float dppmv(float x) {
  return __int_as_float(
      __builtin_amdgcn_mov_dpp(__float_as_int(x), CTRL, 0xF, 0xF, true));
}
__device__ __forceinline__ float rowsum16(float t) {
  t += dppmv<0x128>(t);   // row_ror:8
  t += dppmv<0x124>(t);   // row_ror:4
  t += dppmv<0x122>(t);   // row_ror:2
  t += dppmv<0x121>(t);   // row_ror:1
  return t;
}
__device__ __forceinline__ float rowmax16(float t) {
  t = fmaxf(t, dppmv<0x128>(t));
  t = fmaxf(t, dppmv<0x124>(t));
  t = fmaxf(t, dppmv<0x122>(t));
  t = fmaxf(t, dppmv<0x121>(t));
  return t;
}

// ---- split fp32 array into bf16 hi/lo (no transpose) ----
__global__ void split_arr(const float* __restrict__ in,
                          u16* __restrict__ hi, u16* __restrict__ lo, int n4) {
  int i = blockIdx.x * 256 + threadIdx.x;
  if (i >= n4) return;
  float4 v = ((const float4*)in)[i];
  u32 h0 = bf16_rne(v.x), h1 = bf16_rne(v.y), h2 = bf16_rne(v.z), h3 = bf16_rne(v.w);
  u32 l0 = bf16_rne(v.x - bf16_val(h0));
  u32 l1 = bf16_rne(v.y - bf16_val(h1));
  u32 l2 = bf16_rne(v.z - bf16_val(h2));
  u32 l3 = bf16_rne(v.w - bf16_val(h3));
  ushort4 hv; hv.x = (u16)h0; hv.y = (u16)h1; hv.z = (u16)h2; hv.w = (u16)h3;
  ushort4 lv; lv.x = (u16)l0; lv.y = (u16)l1; lv.z = (u16)l2; lv.w = (u16)l3;
  ((ushort4*)hi)[i] = hv;
  ((ushort4*)lo)[i] = lv;
}

// ---- transpose each 256x256 fp32 slice and split into bf16 hi/lo arrays ----
__global__ void split_transpose256(const float* __restrict__ in,
                                   u16* __restrict__ hi, u16* __restrict__ lo) {
  __shared__ float tile[32][33];
  const size_t off = (size_t)blockIdx.z * 65536;
  const int tx = threadIdx.x, ty = threadIdx.y;
#pragma unroll
  for (int i = 0; i < 4; ++i) {
    int y = blockIdx.y * 32 + ty + i * 8;
    int x = blockIdx.x * 32 + tx;
    tile[ty + i * 8][tx] = in[off + (size_t)y * 256 + x];
  }
  __syncthreads();
#pragma unroll
  for (int i = 0; i < 4; ++i) {
    float v = tile[tx][ty + i * 8];
    u32 hb = bf16_rne(v);
    u32 lb = bf16_rne(v - bf16_val(hb));
    size_t idx = off + (size_t)(blockIdx.x * 32 + ty + i * 8) * 256 + blockIdx.y * 32 + tx;
    hi[idx] = (u16)hb;
    lo[idx] = (u16)lb;
  }
}

// ---------------- fused priors-GEMM (split-bf16) + dynamic routing ----------------
// ROUND-7 = ROUND-6 + DPP reductions (routing shfl chains moved LDS->VALU pipe).
// M=128/block, 256 threads = 4 waves (pure eg roles), wave tile 128x64
// (acc[8][4] = 128 regs). __launch_bounds__(256, 2): acc alone is 128 regs ->
// occupancy hard-capped at 2 waves/SIMD (rounds 1&5: tighter bounds spill ~GBs).
// W fragments: GLOBAL->VGPR one-k-step prefetch (L2-resident). A in LDS:
// double-buffered 16KB slices via global_load_lds, k-granule XOR swizzle
// (source pre-swizzled, linear LDS dest, readers pick slot q ^ ((li>>1)&3)).
// Row r = mt*16 + q*4 + rr (all rows in every wave); col e = eg*64 + ct*16 + li.
template <int R>
__global__ __launch_bounds__(256, 2) void caps_route(
    const u16* __restrict__ Ahi_g,   // [ab][128 rows][256] bf16-hi
    const u16* __restrict__ Alo_g,
    const u16* __restrict__ Whi,     // [KN][256][256] (transposed [e][d])
    const u16* __restrict__ Wlo,
    u16* __restrict__ o1hi, u16* __restrict__ o1lo,   // stage1 out (split)
    float* __restrict__ outp,                          // stage2 out
    int KN, int stage) {
  constexpr int APB = 128 / R;              // routings per block (1 or 2)
  constexpr int SEG = APB;                  // segments per wave
  constexpr int MTS = 8 / SEG;              // m-tiles per segment
  constexpr int ABS = (R == 128) ? 6 : 5;   // log2(a-blocks in grid)
  __shared__ __align__(16) u16 Ab[2][8192];  // A dbuf: [Ahi(8KB) | Alo(8KB)] per slice
  __shared__ __align__(16) float wlog[4][128];
  __shared__ __align__(16) float probs[128];
  __shared__ float sqpart[2][4];

  const int tid = threadIdx.x;
  const int w = tid >> 6, lane = tid & 63, q = lane >> 4, li = lane & 15;
  const int eg = w;                         // wave = column group
  const int kk = blockIdx.x >> ABS;         // weight slice (h or c)
  const int ab = blockIdx.x & ((1 << ABS) - 1);

  // ---- A staging: wave w stages chunks {2w, 2w+1} of hi and lo (4 DMAs/wave) ----
  const int sub = lane >> 2, p = lane & 3;
  const int gslot = p ^ ((sub >> 1) & 3);              // pre-swizzled k-granule
  const size_t lane_off = (size_t)sub * 256 + gslot * 8;
  const u16* gAh = Ahi_g + (size_t)ab * 32768 + (size_t)(2 * w) * 4096 + lane_off;
  const u16* gAl = Alo_g + (size_t)ab * 32768 + (size_t)(2 * w) * 4096 + lane_off;

  auto STAGE = [&](int ko, int nb) {
    u16* d = &Ab[nb][(2 * w) * 512] + lane * 8;        // linear LDS dest (DMA rule)
    g2l16(gAh + ko, d);
    g2l16(gAh + ko + 4096, d + 512);
    g2l16(gAl + ko, d + 4096);
    g2l16(gAl + ko + 4096, d + 4608);
  };

  // ---- W fragment global pointers (direct global->VGPR, no LDS, no swizzle) ----
  const u16* gWh = Whi + (size_t)kk * 65536 + (size_t)(eg * 64 + li) * 256 + q * 8;
  const u16* gWl = Wlo + (size_t)kk * 65536 + (size_t)(eg * 64 + li) * 256 + q * 8;

  // ---- A fragment read offset (swizzled slot) ----
  const int rslot = q ^ ((li >> 1) & 3);
  const int fbase = li * 32 + rslot * 8;               // u16 units within a chunk

  f32x4 acc[8][4] = {};

  // prologue: W frags for ks=0 -> regs; A slice 0 -> LDS
  bf16x8 bh[4], bl[4];
#pragma unroll
  for (int ct = 0; ct < 4; ++ct) {
    bh[ct] = *(const bf16x8*)(gWh + ct * 4096);
    bl[ct] = *(const bf16x8*)(gWl + ct * 4096);
  }
  STAGE(0, 0);
  asm volatile("s_waitcnt vmcnt(0)" ::: "memory");
  __builtin_amdgcn_s_barrier();

  // ---- GEMM main loop: P = A (128 x 256) @ W[kk] (256 x 256), split-bf16 3-MFMA ----
#pragma unroll
  for (int ks = 0; ks < 8; ++ks) {
    bf16x8 nbh[4], nbl[4];
    if (ks < 7) {
      STAGE((ks + 1) * 32, (ks + 1) & 1);              // A DMA next slice
#pragma unroll
      for (int ct = 0; ct < 4; ++ct) {                 // W regs next slice
        nbh[ct] = *(const bf16x8*)(gWh + ct * 4096 + (ks + 1) * 32);
        nbl[ct] = *(const bf16x8*)(gWl + ct * 4096 + (ks + 1) * 32);
      }
    }
    const u16* aB = &Ab[ks & 1][0] + fbase;
#pragma unroll
    for (int mt = 0; mt < 8; ++mt) {
      bf16x8 ah = *(const bf16x8*)(aB + mt * 512);
      bf16x8 al = *(const bf16x8*)(aB + mt * 512 + 4096);
#pragma unroll
      for (int ct = 0; ct < 4; ++ct) {
        acc[mt][ct] = __builtin_amdgcn_mfma_f32_16x16x32_bf16(al, bh[ct], acc[mt][ct], 0, 0, 0);
        acc[mt][ct] = __builtin_amdgcn_mfma_f32_16x16x32_bf16(ah, bl[ct], acc[mt][ct], 0, 0, 0);
        acc[mt][ct] = __builtin_amdgcn_mfma_f32_16x16x32_bf16(ah, bh[ct], acc[mt][ct], 0, 0, 0);
      }
    }
    asm volatile("s_waitcnt vmcnt(0)" ::: "memory");   // next A slice + W regs landed
    __builtin_amdgcn_s_barrier();
    if (ks < 7) {
#pragma unroll
      for (int ct = 0; ct < 4; ++ct) { bh[ct] = nbh[ct]; bl[ct] = nbl[ct]; }
    }
  }

  // ---- dynamic routing (3 iterations), APB independent routings, all wave-local ----
  const float invR = 1.0f / R;
  float v[SEG][4];
  float lg0 = 0.f, lg1 = 0.f;                          // running logits (all waves)

  for (int iter = 0; iter < 3; ++iter) {
    float4 p4[8];
    if (iter == 0) {
#pragma unroll
      for (int mt = 0; mt < 8; ++mt) {
        p4[mt].x = invR; p4[mt].y = invR; p4[mt].z = invR; p4[mt].w = invR;
      }
    } else {
#pragma unroll
      for (int mt = 0; mt < 8; ++mt)
        p4[mt] = *(const float4*)&probs[mt * 16 + q * 4];
    }
    // s[a][e] = sum_b probs[b] * P[b,e] : in-lane over (mt,rr), shfl over q
    float s[SEG][4];
#pragma unroll
    for (int sg = 0; sg < SEG; ++sg) {
#pragma unroll
      for (int ct = 0; ct < 4; ++ct) {
        float t = 0.f;
#pragma unroll
        for (int mi = 0; mi < MTS; ++mi) {
          const int mt = sg * MTS + mi;
          t += p4[mt].x * acc[mt][ct][0] + p4[mt].y * acc[mt][ct][1] +
               p4[mt].z * acc[mt][ct][2] + p4[mt].w * acc[mt][ct][3];
        }
        t += __shfl_xor(t, 16);
        t += __shfl_xor(t, 32);
        s[sg][ct] = t;
      }
    }
    // squash: sq_a = sum_e s_a[e]^2 over 256 e (DPP over li, LDS over eg)
#pragma unroll
    for (int sg = 0; sg < SEG; ++sg) {
      float ss = s[sg][0] * s[sg][0] + s[sg][1] * s[sg][1] +
                 s[sg][2] * s[sg][2] + s[sg][3] * s[sg][3];
      ss = rowsum16(ss);
      if (lane == 0) sqpart[sg][eg] = ss;
    }
    __syncthreads();
#pragma unroll
    for (int sg = 0; sg < SEG; ++sg) {
      float sq = sqpart[sg][0] + sqpart[sg][1] + sqpart[sg][2] + sqpart[sg][3];
      float scale = (sq > 0.f) ? sq / ((1.0f + sq) * sqrtf(sq)) : 0.f;
#pragma unroll
      for (int ct = 0; ct < 4; ++ct) v[sg][ct] = s[sg][ct] * scale;
    }

    if (iter < 2) {
      // logits[b] += sum_e P[b,e] * v[a(b)][e] : in-lane over ct, DPP over li, LDS over eg
#pragma unroll
      for (int mt = 0; mt < 8; ++mt) {
        const int sg = mt / MTS;
        float tt[4];
#pragma unroll
        for (int rr = 0; rr < 4; ++rr) {
          float t = acc[mt][0][rr] * v[sg][0] + acc[mt][1][rr] * v[sg][1] +
                    acc[mt][2][rr] * v[sg][2] + acc[mt][3][rr] * v[sg][3];
          tt[rr] = rowsum16(t);
        }
        if (li == 0)
          *(float4*)&wlog[eg][mt * 16 + q * 4] = make_float4(tt[0], tt[1], tt[2], tt[3]);
      }
      __syncthreads();
      // all-wave redundant softmax (identical values; each wave reads its own writes)
      if (R == 128) {
        int r0 = lane, r1 = lane + 64;   // one routing over 128 rows
        lg0 += wlog[0][r0] + wlog[1][r0] + wlog[2][r0] + wlog[3][r0];
        lg1 += wlog[0][r1] + wlog[1][r1] + wlog[2][r1] + wlog[3][r1];
        float m = fmaxf(lg0, lg1);
        m = rowmax16(m);
        m = fmaxf(m, __shfl_xor(m, 16));
        m = fmaxf(m, __shfl_xor(m, 32));
        float e0 = __expf(lg0 - m), e1 = __expf(lg1 - m);
        float zz = e0 + e1;
        zz = rowsum16(zz);
        zz += __shfl_xor(zz, 16);
        zz += __shfl_xor(zz, 32);
        float inv = 1.0f / zz;
        probs[r0] = e0 * inv;
        probs[r1] = e1 * inv;
      } else {
        int r0 = lane, r1 = lane + 64;   // two routings (rows 0..63 = a0, 64..127 = a1)
        lg0 += wlog[0][r0] + wlog[1][r0] + wlog[2][r0] + wlog[3][r0];
        lg1 += wlog[0][r1] + wlog[1][r1] + wlog[2][r1] + wlog[3][r1];
        float m0 = rowmax16(lg0), m1 = rowmax16(lg1);
        m0 = fmaxf(m0, __shfl_xor(m0, 16));
        m0 = fmaxf(m0, __shfl_xor(m0, 32));
        m1 = fmaxf(m1, __shfl_xor(m1, 16));
        m1 = fmaxf(m1, __shfl_xor(m1, 32));
        float e0 = __expf(lg0 - m0), e1 = __expf(lg1 - m1);
        float z0 = rowsum16(e0), z1 = rowsum16(e1);
        z0 += __shfl_xor(z0, 16);
        z0 += __shfl_xor(z0, 32);
        z1 += __shfl_xor(z1, 16);
        z1 += __shfl_xor(z1, 32);
        probs[r0] = e0 / z0;
        probs[r1] = e1 / z1;
      }
      asm volatile("s_waitcnt lgkmcnt(0)" ::: "memory");  // writes land before next-iter reads
    }
  }

  // ---- epilogue. stage1 -> split out1[a][kk][e]; stage2 -> fp32 out[kk][a][e] ----
  if (q == 0) {
#pragma unroll
    for (int sg = 0; sg < SEG; ++sg) {
      const int ag = ab * APB + sg;      // global a
      if (stage == 1) {
        size_t ob = ((size_t)ag * KN + kk) * 256;
#pragma unroll
        for (int ct = 0; ct < 4; ++ct) {
          int e = eg * 64 + ct * 16 + li;
          u32 hb = bf16_rne(v[sg][ct]);
          u32 lb = bf16_rne(v[sg][ct] - bf16_val(hb));
          o1hi[ob + e] = (u16)hb;
          o1lo[ob + e] = (u16)lb;
        }
      } else {
        size_t ob = ((size_t)kk * 64 + ag) * 256;
#pragma unroll
        for (int ct = 0; ct < 4; ++ct) {
          int e = eg * 64 + ct * 16 + li;
          outp[ob + e] = v[sg][ct];
        }
      }
    }
  }
}

extern "C" void kernel_launch(void* const* d_in, const int* in_sizes, int n_in,
                              void* d_out, int out_size, void* d_ws, size_t ws_size,
                              hipStream_t stream) {
  const float* x  = (const float*)d_in[0];   // [64][128][256]
  const float* w1 = (const float*)d_in[1];   // [64][256][256]
  const float* wc = (const float*)d_in[2];   // [32][256][256]
  float* out = (float*)d_out;                // [32][64][256]

  char* ws = (char*)d_ws;
  u16* w1hi = (u16*)(ws);                    // 8 MB
  u16* w1lo = (u16*)(ws + (8u << 20));       // 8 MB
  u16* wchi = (u16*)(ws + (16u << 20));      // 4 MB
  u16* wclo = (u16*)(ws + (20u << 20));      // 4 MB
  u16* xhi  = (u16*)(ws + (24u << 20));      // 4 MB
  u16* xlo  = (u16*)(ws + (28u << 20));      // 4 MB
  u16* o1hi = (u16*)(ws + (32u << 20));      // 2 MB
  u16* o1lo = (u16*)(ws + (34u << 20));      // 2 MB

  split_arr<<<2048, 256, 0, stream>>>(x, xhi, xlo, 524288);
  split_transpose256<<<dim3(8, 8, 64), dim3(32, 8), 0, stream>>>(w1, w1hi, w1lo);
  split_transpose256<<<dim3(8, 8, 32), dim3(32, 8), 0, stream>>>(wc, wchi, wclo);
  // stage 1: 64 kk x 64 a-blocks (M=128 = 1 routing of R=128), 2 blocks/CU (reg-capped)
  caps_route<128><<<64 * 64, 256, 0, stream>>>(xhi, xlo, w1hi, w1lo, o1hi, o1lo, nullptr, 64, 1);
  // stage 2: 32 kk x 32 a-blocks (M=128 = 2 routings of R=64), 2 blocks/CU
  caps_route<64><<<32 * 32, 256, 0, stream>>>(o1hi, o1lo, wchi, wclo, nullptr, nullptr, out, 32, 2);
}

// Round 8
// 335.214 us; speedup vs baseline: 3.9393x; 1.0100x over previous
//
#include <hip/hip_runtime.h>
#include <hip/hip_bf16.h>

typedef __attribute__((ext_vector_type(8))) short bf16x8;
typedef __attribute__((ext_vector_type(4))) float f32x4;
typedef unsigned short u16;
typedef unsigned int u32;

__device__ __forceinline__ u32 bf16_rne(float f) {
  u32 u = __float_as_uint(f);
  return (u + 0x7FFFu + ((u >> 16) & 1u)) >> 16;
}
__device__ __forceinline__ float bf16_val(u32 b) { return __uint_as_float(b << 16); }

__device__ __forceinline__ void g2l16(const u16* g, u16* l) {
  __builtin_amdgcn_global_load_lds(
      (const __attribute__((address_space(1))) u32*)g,
      (__attribute__((address_space(3))) u32*)l, 16, 0, 0);
}

// ---- DPP rotation reduce within a 16-lane row: VALU pipe, not LDS ----
template <int CTRL>
__device__ __forceinline__ float dppmv(float x) {
  return __int_as_float(
      __builtin_amdgcn_mov_dpp(__float_as_int(x), CTRL, 0xF, 0xF, true));
}
__device__ __forceinline__ float rowsum16(float t) {
  t += dppmv<0x128>(t);   // row_ror:8
  t += dppmv<0x124>(t);   // row_ror:4
  t += dppmv<0x122>(t);   // row_ror:2
  t += dppmv<0x121>(t);   // row_ror:1
  return t;
}
__device__ __forceinline__ float rowmax16(float t) {
  t = fmaxf(t, dppmv<0x128>(t));
  t = fmaxf(t, dppmv<0x124>(t));
  t = fmaxf(t, dppmv<0x122>(t));
  t = fmaxf(t, dppmv<0x121>(t));
  return t;
}

// ---- split fp32 array into bf16 hi/lo (no transpose) ----
__global__ void split_arr(const float* __restrict__ in,
                          u16* __restrict__ hi, u16* __restrict__ lo, int n4) {
  int i = blockIdx.x * 256 + threadIdx.x;
  if (i >= n4) return;
  float4 v = ((const float4*)in)[i];
  u32 h0 = bf16_rne(v.x), h1 = bf16_rne(v.y), h2 = bf16_rne(v.z), h3 = bf16_rne(v.w);
  u32 l0 = bf16_rne(v.x - bf16_val(h0));
  u32 l1 = bf16_rne(v.y - bf16_val(h1));
  u32 l2 = bf16_rne(v.z - bf16_val(h2));
  u32 l3 = bf16_rne(v.w - bf16_val(h3));
  ushort4 hv; hv.x = (u16)h0; hv.y = (u16)h1; hv.z = (u16)h2; hv.w = (u16)h3;
  ushort4 lv; lv.x = (u16)l0; lv.y = (u16)l1; lv.z = (u16)l2; lv.w = (u16)l3;
  ((ushort4*)hi)[i] = hv;
  ((ushort4*)lo)[i] = lv;
}

// ---- transpose each 256x256 fp32 slice and split into bf16 hi/lo arrays ----
__global__ void split_transpose256(const float* __restrict__ in,
                                   u16* __restrict__ hi, u16* __restrict__ lo) {
  __shared__ float tile[32][33];
  const size_t off = (size_t)blockIdx.z * 65536;
  const int tx = threadIdx.x, ty = threadIdx.y;
#pragma unroll
  for (int i = 0; i < 4; ++i) {
    int y = blockIdx.y * 32 + ty + i * 8;
    int x = blockIdx.x * 32 + tx;
    tile[ty + i * 8][tx] = in[off + (size_t)y * 256 + x];
  }
  __syncthreads();
#pragma unroll
  for (int i = 0; i < 4; ++i) {
    float v = tile[tx][ty + i * 8];
    u32 hb = bf16_rne(v);
    u32 lb = bf16_rne(v - bf16_val(hb));
    size_t idx = off + (size_t)(blockIdx.x * 32 + ty + i * 8) * 256 + blockIdx.y * 32 + tx;
    hi[idx] = (u16)hb;
    lo[idx] = (u16)lb;
  }
}

// ---------------- fused priors-GEMM (split-bf16) + dynamic routing ----------------
// ROUND-8 = ROUND-7 + SYNC-POINT HALVING (round-7 accounting: ~29% of wall is
// all-wave stall at ~17 sync points; both co-resident blocks run in lockstep).
//  (a) GEMM pair-steps: 2 k-slices per barrier. A ring = 4 x 16KB slots (pair-level
//      double buffer). Next pair's 8 DMAs issued at pair start (pinned oldest via
//      sched_barrier), pair ends with counted s_waitcnt vmcnt(8) -> A drained,
//      next-slice W loads stay IN FLIGHT across the barrier (T4; round-6/7's
//      vmcnt(0) drained them every step). 9 GEMM syncs -> 4.
//  (b) Routing single barrier/iter: logits pass computed from UNSCALED s
//      (P.v = scale*(P.s), scale applied post-barrier), wlog/sqpart double-
//      buffered by iter parity (kills WAR barrier). 6 routing syncs -> 3.
// M=128/block, 256 threads = 4 waves (pure eg roles), wave tile 128x64
// (acc[8][4] = 128 regs). __launch_bounds__(256,2): acc alone is 128 regs ->
// 2 waves/SIMD cap (rounds 1&5: tighter bounds spill GBs). W frags GLOBAL->VGPR
// one-slice prefetch (L2-resident). A via global_load_lds, k-granule XOR swizzle
// (source pre-swizzled, linear LDS dest, readers pick slot q ^ ((li>>1)&3)).
template <int R>
__global__ __launch_bounds__(256, 2) void caps_route(
    const u16* __restrict__ Ahi_g,   // [ab][128 rows][256] bf16-hi
    const u16* __restrict__ Alo_g,
    const u16* __restrict__ Whi,     // [KN][256][256] (transposed [e][d])
    const u16* __restrict__ Wlo,
    u16* __restrict__ o1hi, u16* __restrict__ o1lo,   // stage1 out (split)
    float* __restrict__ outp,                          // stage2 out
    int KN, int stage) {
  constexpr int APB = 128 / R;              // routings per block (1 or 2)
  constexpr int SEG = APB;                  // segments per wave
  constexpr int MTS = 8 / SEG;              // m-tiles per segment
  constexpr int ABS = (R == 128) ? 6 : 5;   // log2(a-blocks in grid)
  __shared__ __align__(16) u16 Ab[4][8192];  // A ring: 4 slices (pair-level dbuf)
  __shared__ __align__(16) float wlog[2][4][128];   // iter-parity double buffer
  __shared__ __align__(16) float probs[128];
  __shared__ float sqpart[2][2][4];

  const int tid = threadIdx.x;
  const int w = tid >> 6, lane = tid & 63, q = lane >> 4, li = lane & 15;
  const int eg = w;                         // wave = column group
  const int kk = blockIdx.x >> ABS;         // weight slice (h or c)
  const int ab = blockIdx.x & ((1 << ABS) - 1);

  // ---- A staging: wave w stages chunks {2w, 2w+1} of hi and lo (4 DMAs/slice) ----
  const int sub = lane >> 2, p2 = lane & 3;
  const int gslot = p2 ^ ((sub >> 1) & 3);             // pre-swizzled k-granule
  const size_t lane_off = (size_t)sub * 256 + gslot * 8;
  const u16* gAh = Ahi_g + (size_t)ab * 32768 + (size_t)(2 * w) * 4096 + lane_off;
  const u16* gAl = Alo_g + (size_t)ab * 32768 + (size_t)(2 * w) * 4096 + lane_off;

  auto STAGE = [&](int ko, int slot) {
    u16* d = &Ab[slot][(2 * w) * 512] + lane * 8;      // linear LDS dest (DMA rule)
    g2l16(gAh + ko, d);
    g2l16(gAh + ko + 4096, d + 512);
    g2l16(gAl + ko, d + 4096);
    g2l16(gAl + ko + 4096, d + 4608);
  };

  // ---- W fragment global pointers (direct global->VGPR) ----
  const u16* gWh = Whi + (size_t)kk * 65536 + (size_t)(eg * 64 + li) * 256 + q * 8;
  const u16* gWl = Wlo + (size_t)kk * 65536 + (size_t)(eg * 64 + li) * 256 + q * 8;

  // ---- A fragment read offset (swizzled slot) ----
  const int rslot = q ^ ((li >> 1) & 3);
  const int fbase = li * 32 + rslot * 8;               // u16 units within a chunk

  f32x4 acc[8][4] = {};

#define MFMA_SLICE(slot)                                                      \
  do {                                                                        \
    const u16* aB = &Ab[slot][0] + fbase;                                     \
    _Pragma("unroll")                                                         \
    for (int mt = 0; mt < 8; ++mt) {                                          \
      bf16x8 ah = *(const bf16x8*)(aB + mt * 512);                            \
      bf16x8 al = *(const bf16x8*)(aB + mt * 512 + 4096);                     \
      _Pragma("unroll")                                                       \
      for (int ct = 0; ct < 4; ++ct) {                                        \
        acc[mt][ct] = __builtin_amdgcn_mfma_f32_16x16x32_bf16(al, bh[ct], acc[mt][ct], 0, 0, 0); \
        acc[mt][ct] = __builtin_amdgcn_mfma_f32_16x16x32_bf16(ah, bl[ct], acc[mt][ct], 0, 0, 0); \
        acc[mt][ct] = __builtin_amdgcn_mfma_f32_16x16x32_bf16(ah, bh[ct], acc[mt][ct], 0, 0, 0); \
      }                                                                       \
    }                                                                         \
  } while (0)

  // prologue: W(0) -> regs; A slices 0,1 -> slots 0,1
  bf16x8 bh[4], bl[4];
#pragma unroll
  for (int ct = 0; ct < 4; ++ct) {
    bh[ct] = *(const bf16x8*)(gWh + ct * 4096);
    bl[ct] = *(const bf16x8*)(gWl + ct * 4096);
  }
  STAGE(0, 0);
  STAGE(32, 1);
  asm volatile("s_waitcnt vmcnt(0)" ::: "memory");
  __builtin_amdgcn_s_barrier();

  // ---- GEMM main loop: 4 pair-steps, one sync each ----
#pragma unroll
  for (int p = 0; p < 4; ++p) {
    const int s0 = 2 * p, s1 = 2 * p + 1;
    if (p < 3) {                                       // next pair's A DMAs (oldest)
      STAGE((s0 + 2) * 32, (s0 + 2) & 3);
      STAGE((s1 + 2) * 32, (s1 + 2) & 3);
      __builtin_amdgcn_sched_barrier(0);               // pin DMAs before W loads
    }
    bf16x8 nbh[4], nbl[4];
#pragma unroll
    for (int ct = 0; ct < 4; ++ct) {                   // W(s1) prefetch
      nbh[ct] = *(const bf16x8*)(gWh + ct * 4096 + s1 * 32);
      nbl[ct] = *(const bf16x8*)(gWl + ct * 4096 + s1 * 32);
    }
    MFMA_SLICE(s0 & 3);
#pragma unroll
    for (int ct = 0; ct < 4; ++ct) { bh[ct] = nbh[ct]; bl[ct] = nbl[ct]; }
    if (p < 3) {
#pragma unroll
      for (int ct = 0; ct < 4; ++ct) {                 // W(s0+2) prefetch
        nbh[ct] = *(const bf16x8*)(gWh + ct * 4096 + (s0 + 2) * 32);
        nbl[ct] = *(const bf16x8*)(gWl + ct * 4096 + (s0 + 2) * 32);
      }
    }
    MFMA_SLICE(s1 & 3);
    if (p < 3) {
#pragma unroll
      for (int ct = 0; ct < 4; ++ct) { bh[ct] = nbh[ct]; bl[ct] = nbl[ct]; }
      asm volatile("s_waitcnt vmcnt(8)" ::: "memory"); // A(p+1) drained; W stays in flight
      __builtin_amdgcn_s_barrier();
    }
  }
#undef MFMA_SLICE

  // ---- dynamic routing (3 iterations), 1 barrier per iter ----
  const float invR = 1.0f / R;
  float v[SEG][4];
  float scl[SEG];
  float lg0 = 0.f, lg1 = 0.f;                          // running logits (all waves)

  for (int iter = 0; iter < 3; ++iter) {
    const int par = iter & 1;
    float4 p4[8];
    if (iter == 0) {
#pragma unroll
      for (int mt = 0; mt < 8; ++mt) {
        p4[mt].x = invR; p4[mt].y = invR; p4[mt].z = invR; p4[mt].w = invR;
      }
    } else {
#pragma unroll
      for (int mt = 0; mt < 8; ++mt)
        p4[mt] = *(const float4*)&probs[mt * 16 + q * 4];
    }
    // s[a][e] = sum_b probs[b] * P[b,e] : in-lane over (mt,rr), shfl over q
    float s[SEG][4];
#pragma unroll
    for (int sg = 0; sg < SEG; ++sg) {
#pragma unroll
      for (int ct = 0; ct < 4; ++ct) {
        float t = 0.f;
#pragma unroll
        for (int mi = 0; mi < MTS; ++mi) {
          const int mt = sg * MTS + mi;
          t += p4[mt].x * acc[mt][ct][0] + p4[mt].y * acc[mt][ct][1] +
               p4[mt].z * acc[mt][ct][2] + p4[mt].w * acc[mt][ct][3];
        }
        t += __shfl_xor(t, 16);
        t += __shfl_xor(t, 32);
        s[sg][ct] = t;
      }
    }
    // squash partials: sq_a = sum_e s_a[e]^2 (DPP over li; eg exchange via LDS)
#pragma unroll
    for (int sg = 0; sg < SEG; ++sg) {
      float ss = s[sg][0] * s[sg][0] + s[sg][1] * s[sg][1] +
                 s[sg][2] * s[sg][2] + s[sg][3] * s[sg][3];
      ss = rowsum16(ss);
      if (lane == 0) sqpart[par][sg][eg] = ss;
    }
    // logits partials with UNSCALED s (P.v = scale*(P.s); scale applied after)
    if (iter < 2) {
#pragma unroll
      for (int mt = 0; mt < 8; ++mt) {
        const int sg = mt / MTS;
        float tt[4];
#pragma unroll
        for (int rr = 0; rr < 4; ++rr) {
          float t = acc[mt][0][rr] * s[sg][0] + acc[mt][1][rr] * s[sg][1] +
                    acc[mt][2][rr] * s[sg][2] + acc[mt][3][rr] * s[sg][3];
          tt[rr] = rowsum16(t);
        }
        if (li == 0)
          *(float4*)&wlog[par][eg][mt * 16 + q * 4] =
              make_float4(tt[0], tt[1], tt[2], tt[3]);
      }
    }
    __syncthreads();                                   // the ONE barrier per iter
    // scale from squash
#pragma unroll
    for (int sg = 0; sg < SEG; ++sg) {
      float sq = sqpart[par][sg][0] + sqpart[par][sg][1] +
                 sqpart[par][sg][2] + sqpart[par][sg][3];
      scl[sg] = (sq > 0.f) ? sq / ((1.0f + sq) * sqrtf(sq)) : 0.f;
#pragma unroll
      for (int ct = 0; ct < 4; ++ct) v[sg][ct] = s[sg][ct] * scl[sg];
    }

    if (iter < 2) {
      // all-wave redundant softmax; logits += scale * sum_eg wlog
      int r0 = lane, r1 = lane + 64;
      float d0 = wlog[par][0][r0] + wlog[par][1][r0] + wlog[par][2][r0] + wlog[par][3][r0];
      float d1 = wlog[par][0][r1] + wlog[par][1][r1] + wlog[par][2][r1] + wlog[par][3][r1];
      if (R == 128) {
        lg0 += scl[0] * d0;
        lg1 += scl[0] * d1;
        float m = fmaxf(lg0, lg1);
        m = rowmax16(m);
        m = fmaxf(m, __shfl_xor(m, 16));
        m = fmaxf(m, __shfl_xor(m, 32));
        float e0 = __expf(lg0 - m), e1 = __expf(lg1 - m);
        float zz = e0 + e1;
        zz = rowsum16(zz);
        zz += __shfl_xor(zz, 16);
        zz += __shfl_xor(zz, 32);
        float inv = 1.0f / zz;
        probs[r0] = e0 * inv;
        probs[r1] = e1 * inv;
      } else {
        lg0 += scl[0] * d0;            // rows 0..63  = routing a0
        lg1 += scl[1] * d1;            // rows 64..127 = routing a1
        float m0 = rowmax16(lg0), m1 = rowmax16(lg1);
        m0 = fmaxf(m0, __shfl_xor(m0, 16));
        m0 = fmaxf(m0, __shfl_xor(m0, 32));
        m1 = fmaxf(m1, __shfl_xor(m1, 16));
        m1 = fmaxf(m1, __shfl_xor(m1, 32));
        float e0 = __expf(lg0 - m0), e1 = __expf(lg1 - m1);
        float z0 = rowsum16(e0), z1 = rowsum16(e1);
        z0 += __shfl_xor(z0, 16);
        z0 += __shfl_xor(z0, 32);
        z1 += __shfl_xor(z1, 16);
        z1 += __shfl_xor(z1, 32);
        probs[r0] = e0 / z0;
        probs[r1] = e1 / z1;
      }
      asm volatile("s_waitcnt lgkmcnt(0)" ::: "memory");  // own writes land before next-iter reads
    }
  }

  // ---- epilogue. stage1 -> split out1[a][kk][e]; stage2 -> fp32 out[kk][a][e] ----
  if (q == 0) {
#pragma unroll
    for (int sg = 0; sg < SEG; ++sg) {
      const int ag = ab * APB + sg;      // global a
      if (stage == 1) {
        size_t ob = ((size_t)ag * KN + kk) * 256;
#pragma unroll
        for (int ct = 0; ct < 4; ++ct) {
          int e = eg * 64 + ct * 16 + li;
          u32 hb = bf16_rne(v[sg][ct]);
          u32 lb = bf16_rne(v[sg][ct] - bf16_val(hb));
          o1hi[ob + e] = (u16)hb;
          o1lo[ob + e] = (u16)lb;
        }
      } else {
        size_t ob = ((size_t)kk * 64 + ag) * 256;
#pragma unroll
        for (int ct = 0; ct < 4; ++ct) {
          int e = eg * 64 + ct * 16 + li;
          outp[ob + e] = v[sg][ct];
        }
      }
    }
  }
}

extern "C" void kernel_launch(void* const* d_in, const int* in_sizes, int n_in,
                              void* d_out, int out_size, void* d_ws, size_t ws_size,
                              hipStream_t stream) {
  const float* x  = (const float*)d_in[0];   // [64][128][256]
  const float* w1 = (const float*)d_in[1];   // [64][256][256]
  const float* wc = (const float*)d_in[2];   // [32][256][256]
  float* out = (float*)d_out;                // [32][64][256]

  char* ws = (char*)d_ws;
  u16* w1hi = (u16*)(ws);                    // 8 MB
  u16* w1lo = (u16*)(ws + (8u << 20));       // 8 MB
  u16* wchi = (u16*)(ws + (16u << 20));      // 4 MB
  u16* wclo = (u16*)(ws + (20u << 20));      // 4 MB
  u16* xhi  = (u16*)(ws + (24u << 20));      // 4 MB
  u16* xlo  = (u16*)(ws + (28u << 20));      // 4 MB
  u16* o1hi = (u16*)(ws + (32u << 20));      // 2 MB
  u16* o1lo = (u16*)(ws + (34u << 20));      // 2 MB

  split_arr<<<2048, 256, 0, stream>>>(x, xhi, xlo, 524288);
  split_transpose256<<<dim3(8, 8, 64), dim3(32, 8), 0, stream>>>(w1, w1hi, w1lo);
  split_transpose256<<<dim3(8, 8, 32), dim3(32, 8), 0, stream>>>(wc, wchi, wclo);
  // stage 1: 64 kk x 64 a-blocks (M=128 = 1 routing of R=128), 2 blocks/CU (reg-capped)
  caps_route<128><<<64 * 64, 256, 0, stream>>>(xhi, xlo, w1hi, w1lo, o1hi, o1lo, nullptr, 64, 1);
  // stage 2: 32 kk x 32 a-blocks (M=128 = 2 routings of R=64), 2 blocks/CU
  caps_route<64><<<32 * 32, 256, 0, stream>>>(o1hi, o1lo, wchi, wclo, nullptr, nullptr, out, 32, 2);
}